// Round 11
// baseline (350.100 us; speedup 1.0000x reference)
//
#include <hip/hip_runtime.h>
#include <hip/hip_bf16.h>

// LossVariance — B=16, C=32, H=W=512, L=64.
// loss = mean_b [ sum_{l!=0} var_sum(b,l) / (num_unique_b + 1e-8) ]
// var_sum(b,l) = (q - sum_c s_c^2/cnt) / (cnt-1), cnt>1 else 0
//   s[b,l,c] = sum_{p: t=l} x[b,c,p]   -> one-hot GEMM on MFMA
//   q[b,l]   = sum_c ss[b,l,c]         -> same MFMAs, B = bf16(x*x)
//   cnt      = LDS histogram
// R11: R6 config exactly (DEPTH=4, launch_bounds(256,4), f2bf pack) +
//      finalize folded into seg via last-block counter (device-scope
//      fetch_add + agent-scope acquire loads) -> 2-kernel chain.

#define LBL 64
#define CH 32
constexpr int PIX   = 512 * 512;
constexpr int BATCH = 16;
constexpr int BPB   = 64;                  // pixel-blocks per batch
constexpr int TPB   = 256;                 // 4 waves
constexpr int PPB   = PIX / BPB;           // 4096 pixels per block
constexpr int HALF_PIX = PPB / 2;          // 2048 pixels per wave
constexpr int KSTEPS   = HALF_PIX / 32;    // 64 K-steps of 32 pixels
constexpr int NBLOCKS  = BPB * BATCH;      // 1024

typedef __attribute__((ext_vector_type(8))) short    bf16x8;
typedef __attribute__((ext_vector_type(4))) float    f32x4;
typedef __attribute__((ext_vector_type(4))) unsigned u32x4;

// ws layout (floats): s_g[B][L][CH] | q_g[B][L] | c_g[B][L] | done-counter
constexpr int Q_OFF     = BATCH * LBL * CH;        // 32768
constexpr int C_OFF     = Q_OFF + BATCH * LBL;     // 33792
constexpr int CNT_OFF   = C_OFF + BATCH * LBL;     // 34816
constexpr int WS_FLOATS = CNT_OFF + 1;             // 34817

static __device__ __forceinline__ short f2bf(float f) {
    __hip_bfloat16 h = __float2bfloat16(f);
    return __builtin_bit_cast(short, h);
}
static __device__ __forceinline__ bf16x8 pack8(float4 a, float4 b) {
    bf16x8 r;
    r[0]=f2bf(a.x); r[1]=f2bf(a.y); r[2]=f2bf(a.z); r[3]=f2bf(a.w);
    r[4]=f2bf(b.x); r[5]=f2bf(b.y); r[6]=f2bf(b.z); r[7]=f2bf(b.w);
    return r;
}
static __device__ __forceinline__ float4 sq4(float4 a) {
    return make_float4(a.x*a.x, a.y*a.y, a.z*a.z, a.w*a.w);
}
static __device__ __forceinline__ float agent_load(const float* p) {
    return __hip_atomic_load(p, __ATOMIC_RELAXED, __HIP_MEMORY_SCOPE_AGENT);
}

__global__ __launch_bounds__(TPB) void zero_ws(float* __restrict__ ws) {
    const int i = blockIdx.x * TPB + threadIdx.x;
    if (i < WS_FLOATS) ws[i] = 0.f;
}

__global__ __launch_bounds__(TPB, 4) void seg_onehot_mfma(
    const float* __restrict__ x, const int* __restrict__ tg,
    float* __restrict__ s_g, float* __restrict__ q_g, float* __restrict__ c_g,
    unsigned* __restrict__ done, float* __restrict__ out)
{
    __shared__ float    s_blk[LBL][CH + 1];
    __shared__ float    ss_blk[LBL][CH + 1];
    __shared__ unsigned c_hist[LBL];
    __shared__ __align__(16) unsigned char lab8[PPB];   // 4 KiB packed labels
    __shared__ unsigned s_last;
    __shared__ float    partial[4];

    const int b    = blockIdx.y;
    const int tid  = threadIdx.x;
    const int wave = tid >> 6;
    const int lane = tid & 63;
    const int p0   = blockIdx.x * PPB;

    // ---- per-wave geometry (early so x prefetch issues first)
    const int kgrp   = lane >> 4;          // K sub-block 0..3 (8 pixels each)
    const int lo     = lane & 15;          // A: label-in-tile / B: channel-in-tile
    const int half   = wave >> 1;          // pixel half
    const int ch_off = (wave & 1) * 16;    // channel half
    const int lp0    = half * HALF_PIX + kgrp * 8;        // block-local pixel idx
    const float* xA  = x + ((size_t)b * CH + ch_off + lo) * PIX + p0 + lp0;

    // ---- issue 4-deep x prefetch immediately (in flight during label pass)
    float4 Ux[4][2];
    #pragma unroll
    for (int s = 0; s < 4; ++s) {
        Ux[s][0] = *reinterpret_cast<const float4*>(xA + s * 32);
        Ux[s][1] = *reinterpret_cast<const float4*>(xA + s * 32 + 4);
    }

    // ---- zero LDS
    for (int i = tid; i < LBL * (CH + 1); i += TPB) {
        (&s_blk[0][0])[i]  = 0.f;
        (&ss_blk[0][0])[i] = 0.f;
    }
    if (tid < LBL) c_hist[tid] = 0u;
    __syncthreads();   // c_hist zeroed before ANY wave's atomics

    // ---- label pass: load 16 labels/thread, pack to u8, hist
    const int* tb = tg + (size_t)b * PIX;
    {
        const int gbase = p0 + tid * 16;
        int4 lv[4];
        #pragma unroll
        for (int j = 0; j < 4; ++j)
            lv[j] = *reinterpret_cast<const int4*>(tb + gbase + j * 4);
        u32x4 pk;
        #pragma unroll
        for (int j = 0; j < 4; ++j)
            pk[j] = (unsigned)lv[j].x | ((unsigned)lv[j].y << 8) |
                    ((unsigned)lv[j].z << 16) | ((unsigned)lv[j].w << 24);
        *reinterpret_cast<u32x4*>(&lab8[tid * 16]) = pk;
        #pragma unroll
        for (int j = 0; j < 4; ++j) {
            atomicAdd(&c_hist[lv[j].x], 1u);
            atomicAdd(&c_hist[lv[j].y], 1u);
            atomicAdd(&c_hist[lv[j].z], 1u);
            atomicAdd(&c_hist[lv[j].w], 1u);
        }
    }
    __syncthreads();

    // ---- label prefetch from LDS (4 sets, 8 labels each)
    uint2 Lb[4];
    #pragma unroll
    for (int s = 0; s < 4; ++s)
        Lb[s] = *reinterpret_cast<const uint2*>(&lab8[lp0 + s * 32]);

    f32x4 acc_s[4], acc_q[4];
    #pragma unroll
    for (int m = 0; m < 4; ++m) {
        acc_s[m] = (f32x4){0.f, 0.f, 0.f, 0.f};
        acc_q[m] = (f32x4){0.f, 0.f, 0.f, 0.f};
    }

    const float*         xP = xA;          // points at current ks
    const unsigned char* lP = &lab8[lp0];

    for (int ks = 0; ks < KSTEPS; ks += 4) {
        // prefetch source for steps ks+4..ks+7 (wraps to start on last iter;
        // wrapped loads are never consumed, just keep addresses in-bounds)
        const bool last = (ks + 4 >= KSTEPS);
        const float*         xQ = last ? xA          : xP + 4 * 32;
        const unsigned char* lQ = last ? &lab8[lp0]  : lP + 4 * 32;

        #pragma unroll
        for (int u = 0; u < 4; ++u) {
            const float4 U0 = Ux[u][0];
            const float4 U1 = Ux[u][1];
            const uint2  L  = Lb[u];

            // refill this set for step ks+4+u (issued before the heavy VALU)
            Ux[u][0] = *reinterpret_cast<const float4*>(xQ + u * 32);
            Ux[u][1] = *reinterpret_cast<const float4*>(xQ + u * 32 + 4);
            Lb[u]    = *reinterpret_cast<const uint2*>(lQ + u * 32);

            const bf16x8 bx = pack8(U0, U1);
            const bf16x8 bq = pack8(sq4(U0), sq4(U1));

            const unsigned e0 = (L.x      ) & 0xFFu;
            const unsigned e1 = (L.x >>  8) & 0xFFu;
            const unsigned e2 = (L.x >> 16) & 0xFFu;
            const unsigned e3 = (L.x >> 24);
            const unsigned e4 = (L.y      ) & 0xFFu;
            const unsigned e5 = (L.y >>  8) & 0xFFu;
            const unsigned e6 = (L.y >> 16) & 0xFFu;
            const unsigned e7 = (L.y >> 24);

            #pragma unroll
            for (int m = 0; m < 4; ++m) {
                const unsigned tgt = (unsigned)(lo + m * 16);
                u32x4 w;
                w[0] = ((e0 == tgt) ? 0x00003F80u : 0u) | ((e1 == tgt) ? 0x3F800000u : 0u);
                w[1] = ((e2 == tgt) ? 0x00003F80u : 0u) | ((e3 == tgt) ? 0x3F800000u : 0u);
                w[2] = ((e4 == tgt) ? 0x00003F80u : 0u) | ((e5 == tgt) ? 0x3F800000u : 0u);
                w[3] = ((e6 == tgt) ? 0x00003F80u : 0u) | ((e7 == tgt) ? 0x3F800000u : 0u);
                const bf16x8 am = __builtin_bit_cast(bf16x8, w);
                acc_s[m] = __builtin_amdgcn_mfma_f32_16x16x32_bf16(am, bx, acc_s[m], 0, 0, 0);
                acc_q[m] = __builtin_amdgcn_mfma_f32_16x16x32_bf16(am, bq, acc_q[m], 0, 0, 0);
            }
        }
        xP += 4 * 32;
        lP += 4 * 32;
    }

    // ---- fragments -> block LDS (C/D: col=lane&15, row=(lane>>4)*4+r)
    #pragma unroll
    for (int m = 0; m < 4; ++m)
        #pragma unroll
        for (int r = 0; r < 4; ++r) {
            const int row = m * 16 + kgrp * 4 + r;
            const int col = ch_off + lo;
            unsafeAtomicAdd(&s_blk[row][col],  acc_s[m][r]);
            unsafeAtomicAdd(&ss_blk[row][col], acc_q[m][r]);
        }
    __syncthreads();

    // ---- flush block partials to global accumulators (atomic; ws pre-zeroed)
    float* sg = s_g + (size_t)b * LBL * CH;
    #pragma unroll
    for (int i = 0; i < 8; ++i) {
        const int idx = tid + i * TPB;          // 0..2047
        unsafeAtomicAdd(&sg[idx], s_blk[idx >> 5][idx & 31]);
    }
    if (tid < LBL) {
        float q = 0.f;
        #pragma unroll
        for (int c = 0; c < CH; ++c) q += ss_blk[tid][c];
        unsafeAtomicAdd(&q_g[b * LBL + tid], q);
        unsafeAtomicAdd(&c_g[b * LBL + tid], (float)c_hist[tid]);
    }

    // ---- last-block finalize
    __threadfence();                       // release this block's flushes
    if (tid == 0) {
        const unsigned old = __hip_atomic_fetch_add(done, 1u, __ATOMIC_ACQ_REL,
                                                    __HIP_MEMORY_SCOPE_AGENT);
        s_last = (old == NBLOCKS - 1) ? 1u : 0u;
    }
    __syncthreads();
    if (s_last) {
        __threadfence();                   // acquire all blocks' flushes
        // 4 waves x 4 batches each; lane = label
        const int l = lane;
        float wsum = 0.f;                  // lane 0 accumulates its wave's batches
        #pragma unroll
        for (int bb = 0; bb < 4; ++bb) {
            const int b2 = wave * 4 + bb;
            const float cnt = agent_load(&c_g[b2 * LBL + l]);
            const float q   = agent_load(&q_g[b2 * LBL + l]);
            const float* sgb = s_g + ((size_t)b2 * LBL + l) * CH;
            float sum2 = 0.f;
            #pragma unroll
            for (int c = 0; c < CH; ++c) {
                const float s = agent_load(&sgb[c]);
                sum2 = fmaf(s, s, sum2);
            }
            float var_sum = 0.f;
            if (cnt > 1.f) var_sum = (q - sum2 / cnt) / (cnt - 1.f);
            float v       = (l != 0) ? var_sum : 0.f;
            float present = (l != 0 && cnt > 0.f) ? 1.f : 0.f;
            #pragma unroll
            for (int off = 32; off > 0; off >>= 1) {
                v       += __shfl_down(v, off);
                present += __shfl_down(present, off);
            }
            if (l == 0) wsum += v / (present + 1e-8f);
        }
        if (l == 0) partial[wave] = wsum;
        __syncthreads();
        if (tid == 0)
            out[0] = (partial[0] + partial[1] + partial[2] + partial[3]) / (float)BATCH;
    }
}

// Fallback if ws is too small: one block per batch, LDS atomics (slow, correct).
__global__ __launch_bounds__(1024) void fallback_all(
    const float* __restrict__ x, const int* __restrict__ tg,
    float* __restrict__ out)
{
    __shared__ float s_l[CH][LBL];
    __shared__ float q_l[LBL];
    __shared__ float c_l[LBL];

    const int b   = blockIdx.x;
    const int tid = threadIdx.x;

    for (int i = tid; i < CH * LBL; i += 1024) (&s_l[0][0])[i] = 0.f;
    if (tid < LBL) { q_l[tid] = 0.f; c_l[tid] = 0.f; }
    __syncthreads();

    const float* xb = x  + (size_t)b * CH * PIX;
    const int*   tb = tg + (size_t)b * PIX;

    for (int base = 0; base < PIX; base += 1024 * 4) {
        const int p = base + tid * 4;
        const int4 lab = *reinterpret_cast<const int4*>(tb + p);
        float q0 = 0.f, q1 = 0.f, q2 = 0.f, q3 = 0.f;
        #pragma unroll 8
        for (int c = 0; c < CH; ++c) {
            const float4 v = *reinterpret_cast<const float4*>(xb + (size_t)c * PIX + p);
            unsafeAtomicAdd(&s_l[c][lab.x], v.x);
            unsafeAtomicAdd(&s_l[c][lab.y], v.y);
            unsafeAtomicAdd(&s_l[c][lab.z], v.z);
            unsafeAtomicAdd(&s_l[c][lab.w], v.w);
            q0 = fmaf(v.x, v.x, q0);
            q1 = fmaf(v.y, v.y, q1);
            q2 = fmaf(v.z, v.z, q2);
            q3 = fmaf(v.w, v.w, q3);
        }
        unsafeAtomicAdd(&q_l[lab.x], q0);
        unsafeAtomicAdd(&q_l[lab.y], q1);
        unsafeAtomicAdd(&q_l[lab.z], q2);
        unsafeAtomicAdd(&q_l[lab.w], q3);
        unsafeAtomicAdd(&c_l[lab.x], 1.f);
        unsafeAtomicAdd(&c_l[lab.y], 1.f);
        unsafeAtomicAdd(&c_l[lab.z], 1.f);
        unsafeAtomicAdd(&c_l[lab.w], 1.f);
    }
    __syncthreads();

    if (tid < LBL) {
        const int l = tid;
        const float cnt = c_l[l];
        const float q   = q_l[l];
        float sum2 = 0.f;
        #pragma unroll
        for (int c = 0; c < CH; ++c) sum2 = fmaf(s_l[c][l], s_l[c][l], sum2);
        float var_sum = 0.f;
        if (cnt > 1.f) var_sum = (q - sum2 / cnt) / (cnt - 1.f);
        float v       = (l != 0) ? var_sum : 0.f;
        float present = (l != 0 && cnt > 0.f) ? 1.f : 0.f;
        #pragma unroll
        for (int off = 32; off > 0; off >>= 1) {
            v       += __shfl_down(v, off);
            present += __shfl_down(present, off);
        }
        if (l == 0)
            unsafeAtomicAdd(out, v / (present + 1e-8f) / (float)BATCH);
    }
}

extern "C" void kernel_launch(void* const* d_in, const int* in_sizes, int n_in,
                              void* d_out, int out_size, void* d_ws, size_t ws_size,
                              hipStream_t stream)
{
    const float* x  = (const float*)d_in[0];
    const int*   tg = (const int*)d_in[1];
    float* out = (float*)d_out;
    float* ws  = (float*)d_ws;

    if (ws_size >= (size_t)WS_FLOATS * sizeof(float)) {
        zero_ws<<<(WS_FLOATS + TPB - 1) / TPB, TPB, 0, stream>>>(ws);
        dim3 grid(BPB, BATCH);
        seg_onehot_mfma<<<grid, TPB, 0, stream>>>(
            x, tg, ws, ws + Q_OFF, ws + C_OFF,
            (unsigned*)(ws + CNT_OFF), out);
    } else {
        hipMemsetAsync(d_out, 0, sizeof(float), stream);
        fallback_all<<<BATCH, 1024, 0, stream>>>(x, tg, out);
    }
}

// Round 12
// 155.322 us; speedup vs baseline: 2.2540x; 2.2540x over previous
//
#include <hip/hip_runtime.h>
#include <hip/hip_bf16.h>

// LossVariance — B=16, C=32, H=W=512, L=64.
// loss = mean_b [ sum_{l!=0} var_sum(b,l) / (num_unique_b + 1e-8) ]
// var_sum(b,l) = (q - sum_c s_c^2/cnt) / (cnt-1), cnt>1 else 0
//   s[b,l,c] = sum_{p: t=l} x[b,c,p]   -> one-hot GEMM on MFMA
//   q[b,l]   = sum_c ss[b,l,c]         -> same MFMAs, B = bf16(x*x)
//   cnt      = LDS histogram
// R12: revert to R6 verbatim (best: 155.7us). R11's fused finalize tail
//      collapsed the kernel to 60 VGPR -> compiler de-pipelined the hot
//      loop (703 GB/s). Keep finalize as a separate tiny kernel so the
//      seg kernel's regalloc stays pipeline-shaped.

#define LBL 64
#define CH 32
constexpr int PIX   = 512 * 512;
constexpr int BATCH = 16;
constexpr int BPB   = 64;                  // pixel-blocks per batch
constexpr int TPB   = 256;                 // 4 waves
constexpr int PPB   = PIX / BPB;           // 4096 pixels per block
constexpr int HALF_PIX = PPB / 2;          // 2048 pixels per wave
constexpr int KSTEPS   = HALF_PIX / 32;    // 64 K-steps of 32 pixels

typedef __attribute__((ext_vector_type(8))) short    bf16x8;
typedef __attribute__((ext_vector_type(4))) float    f32x4;
typedef __attribute__((ext_vector_type(4))) unsigned u32x4;

// ws layout (floats): s_g[B][L][CH] | q_g[B][L] | c_g[B][L]
constexpr int Q_OFF     = BATCH * LBL * CH;        // 32768
constexpr int C_OFF     = Q_OFF + BATCH * LBL;     // 33792
constexpr int WS_FLOATS = C_OFF + BATCH * LBL;     // 34816 (136 KiB)

static __device__ __forceinline__ short f2bf(float f) {
    __hip_bfloat16 h = __float2bfloat16(f);
    return __builtin_bit_cast(short, h);
}
static __device__ __forceinline__ bf16x8 pack8(float4 a, float4 b) {
    bf16x8 r;
    r[0]=f2bf(a.x); r[1]=f2bf(a.y); r[2]=f2bf(a.z); r[3]=f2bf(a.w);
    r[4]=f2bf(b.x); r[5]=f2bf(b.y); r[6]=f2bf(b.z); r[7]=f2bf(b.w);
    return r;
}
static __device__ __forceinline__ float4 sq4(float4 a) {
    return make_float4(a.x*a.x, a.y*a.y, a.z*a.z, a.w*a.w);
}

__global__ __launch_bounds__(TPB) void zero_ws(float* __restrict__ ws) {
    const int i = blockIdx.x * TPB + threadIdx.x;
    if (i < WS_FLOATS) ws[i] = 0.f;
}

__global__ __launch_bounds__(TPB, 4) void seg_onehot_mfma(
    const float* __restrict__ x, const int* __restrict__ tg,
    float* __restrict__ s_g, float* __restrict__ q_g, float* __restrict__ c_g)
{
    __shared__ float    s_blk[LBL][CH + 1];
    __shared__ float    ss_blk[LBL][CH + 1];
    __shared__ unsigned c_hist[LBL];
    __shared__ __align__(16) unsigned char lab8[PPB];   // 4 KiB packed labels

    const int b    = blockIdx.y;
    const int tid  = threadIdx.x;
    const int wave = tid >> 6;
    const int lane = tid & 63;
    const int p0   = blockIdx.x * PPB;

    // ---- per-wave geometry (computed early so x prefetch can issue first)
    const int kgrp   = lane >> 4;          // K sub-block 0..3 (8 pixels each)
    const int lo     = lane & 15;          // A: label-in-tile / B: channel-in-tile
    const int half   = wave >> 1;          // pixel half
    const int ch_off = (wave & 1) * 16;    // channel half
    const int lp0    = half * HALF_PIX + kgrp * 8;        // block-local pixel idx
    const float* xA  = x + ((size_t)b * CH + ch_off + lo) * PIX + p0 + lp0;

    // ---- issue 4-deep x prefetch immediately (in flight during label pass)
    float4 Ux[4][2];
    #pragma unroll
    for (int s = 0; s < 4; ++s) {
        Ux[s][0] = *reinterpret_cast<const float4*>(xA + s * 32);
        Ux[s][1] = *reinterpret_cast<const float4*>(xA + s * 32 + 4);
    }

    // ---- zero LDS
    for (int i = tid; i < LBL * (CH + 1); i += TPB) {
        (&s_blk[0][0])[i]  = 0.f;
        (&ss_blk[0][0])[i] = 0.f;
    }
    if (tid < LBL) c_hist[tid] = 0u;
    __syncthreads();   // c_hist must be zeroed before ANY wave's atomics

    // ---- label pass: load 16 labels/thread, pack to u8, hist
    const int* tb = tg + (size_t)b * PIX;
    {
        const int gbase = p0 + tid * 16;
        int4 lv[4];
        #pragma unroll
        for (int j = 0; j < 4; ++j)
            lv[j] = *reinterpret_cast<const int4*>(tb + gbase + j * 4);
        u32x4 pk;
        #pragma unroll
        for (int j = 0; j < 4; ++j)
            pk[j] = (unsigned)lv[j].x | ((unsigned)lv[j].y << 8) |
                    ((unsigned)lv[j].z << 16) | ((unsigned)lv[j].w << 24);
        *reinterpret_cast<u32x4*>(&lab8[tid * 16]) = pk;
        #pragma unroll
        for (int j = 0; j < 4; ++j) {
            atomicAdd(&c_hist[lv[j].x], 1u);
            atomicAdd(&c_hist[lv[j].y], 1u);
            atomicAdd(&c_hist[lv[j].z], 1u);
            atomicAdd(&c_hist[lv[j].w], 1u);
        }
    }
    __syncthreads();

    // ---- label prefetch from LDS (4 sets, 8 labels each)
    uint2 Lb[4];
    #pragma unroll
    for (int s = 0; s < 4; ++s)
        Lb[s] = *reinterpret_cast<const uint2*>(&lab8[lp0 + s * 32]);

    f32x4 acc_s[4], acc_q[4];
    #pragma unroll
    for (int m = 0; m < 4; ++m) {
        acc_s[m] = (f32x4){0.f, 0.f, 0.f, 0.f};
        acc_q[m] = (f32x4){0.f, 0.f, 0.f, 0.f};
    }

    const float*         xP = xA;          // points at current ks
    const unsigned char* lP = &lab8[lp0];

    for (int ks = 0; ks < KSTEPS; ks += 4) {
        // prefetch source for steps ks+4..ks+7 (wraps to start on last iter;
        // wrapped loads are never consumed, just keep addresses in-bounds)
        const bool last = (ks + 4 >= KSTEPS);
        const float*         xQ = last ? xA          : xP + 4 * 32;
        const unsigned char* lQ = last ? &lab8[lp0]  : lP + 4 * 32;

        #pragma unroll
        for (int u = 0; u < 4; ++u) {
            const float4 U0 = Ux[u][0];
            const float4 U1 = Ux[u][1];
            const uint2  L  = Lb[u];

            // refill this set for step ks+4+u (issued before the heavy VALU)
            Ux[u][0] = *reinterpret_cast<const float4*>(xQ + u * 32);
            Ux[u][1] = *reinterpret_cast<const float4*>(xQ + u * 32 + 4);
            Lb[u]    = *reinterpret_cast<const uint2*>(lQ + u * 32);

            const bf16x8 bx = pack8(U0, U1);
            const bf16x8 bq = pack8(sq4(U0), sq4(U1));

            const unsigned e0 = (L.x      ) & 0xFFu;
            const unsigned e1 = (L.x >>  8) & 0xFFu;
            const unsigned e2 = (L.x >> 16) & 0xFFu;
            const unsigned e3 = (L.x >> 24);
            const unsigned e4 = (L.y      ) & 0xFFu;
            const unsigned e5 = (L.y >>  8) & 0xFFu;
            const unsigned e6 = (L.y >> 16) & 0xFFu;
            const unsigned e7 = (L.y >> 24);

            #pragma unroll
            for (int m = 0; m < 4; ++m) {
                const unsigned tgt = (unsigned)(lo + m * 16);
                u32x4 w;
                w[0] = ((e0 == tgt) ? 0x00003F80u : 0u) | ((e1 == tgt) ? 0x3F800000u : 0u);
                w[1] = ((e2 == tgt) ? 0x00003F80u : 0u) | ((e3 == tgt) ? 0x3F800000u : 0u);
                w[2] = ((e4 == tgt) ? 0x00003F80u : 0u) | ((e5 == tgt) ? 0x3F800000u : 0u);
                w[3] = ((e6 == tgt) ? 0x00003F80u : 0u) | ((e7 == tgt) ? 0x3F800000u : 0u);
                const bf16x8 am = __builtin_bit_cast(bf16x8, w);
                acc_s[m] = __builtin_amdgcn_mfma_f32_16x16x32_bf16(am, bx, acc_s[m], 0, 0, 0);
                acc_q[m] = __builtin_amdgcn_mfma_f32_16x16x32_bf16(am, bq, acc_q[m], 0, 0, 0);
            }
        }
        xP += 4 * 32;
        lP += 4 * 32;
    }

    // ---- fragments -> block LDS (C/D: col=lane&15, row=(lane>>4)*4+r)
    #pragma unroll
    for (int m = 0; m < 4; ++m)
        #pragma unroll
        for (int r = 0; r < 4; ++r) {
            const int row = m * 16 + kgrp * 4 + r;
            const int col = ch_off + lo;
            unsafeAtomicAdd(&s_blk[row][col],  acc_s[m][r]);
            unsafeAtomicAdd(&ss_blk[row][col], acc_q[m][r]);
        }
    __syncthreads();

    // ---- flush block partials to global accumulators (atomic; ws pre-zeroed)
    float* sg = s_g + (size_t)b * LBL * CH;
    #pragma unroll
    for (int i = 0; i < 8; ++i) {
        const int idx = tid + i * TPB;          // 0..2047
        unsafeAtomicAdd(&sg[idx], s_blk[idx >> 5][idx & 31]);
    }
    if (tid < LBL) {
        float q = 0.f;
        #pragma unroll
        for (int c = 0; c < CH; ++c) q += ss_blk[tid][c];
        unsafeAtomicAdd(&q_g[b * LBL + tid], q);
        unsafeAtomicAdd(&c_g[b * LBL + tid], (float)c_hist[tid]);
    }
}

__global__ __launch_bounds__(1024) void finalize(
    const float* __restrict__ s_g, const float* __restrict__ q_g,
    const float* __restrict__ c_g, float* __restrict__ out)
{
    const int t = threadIdx.x;        // 0..1023
    const int b = t >> 6;             // one wave per batch
    const int l = t & 63;

    const float cnt = c_g[b * LBL + l];
    const float q   = q_g[b * LBL + l];
    const float* sg = s_g + ((size_t)b * LBL + l) * CH;
    float sum2 = 0.f;
    #pragma unroll
    for (int c = 0; c < CH; ++c) sum2 = fmaf(sg[c], sg[c], sum2);

    float var_sum = 0.f;
    if (cnt > 1.f) var_sum = (q - sum2 / cnt) / (cnt - 1.f);

    float v       = (l != 0) ? var_sum : 0.f;
    float present = (l != 0 && cnt > 0.f) ? 1.f : 0.f;

    #pragma unroll
    for (int off = 32; off > 0; off >>= 1) {
        v       += __shfl_down(v, off);
        present += __shfl_down(present, off);
    }

    __shared__ float partial[BATCH];
    if (l == 0) partial[b] = v / (present + 1e-8f);
    __syncthreads();
    if (t == 0) {
        float acc = 0.f;
        #pragma unroll
        for (int i = 0; i < BATCH; ++i) acc += partial[i];
        out[0] = acc / (float)BATCH;
    }
}

// Fallback if ws is too small: one block per batch, LDS atomics (slow, correct).
__global__ __launch_bounds__(1024) void fallback_all(
    const float* __restrict__ x, const int* __restrict__ tg,
    float* __restrict__ out)
{
    __shared__ float s_l[CH][LBL];
    __shared__ float q_l[LBL];
    __shared__ float c_l[LBL];

    const int b   = blockIdx.x;
    const int tid = threadIdx.x;

    for (int i = tid; i < CH * LBL; i += 1024) (&s_l[0][0])[i] = 0.f;
    if (tid < LBL) { q_l[tid] = 0.f; c_l[tid] = 0.f; }
    __syncthreads();

    const float* xb = x  + (size_t)b * CH * PIX;
    const int*   tb = tg + (size_t)b * PIX;

    for (int base = 0; base < PIX; base += 1024 * 4) {
        const int p = base + tid * 4;
        const int4 lab = *reinterpret_cast<const int4*>(tb + p);
        float q0 = 0.f, q1 = 0.f, q2 = 0.f, q3 = 0.f;
        #pragma unroll 8
        for (int c = 0; c < CH; ++c) {
            const float4 v = *reinterpret_cast<const float4*>(xb + (size_t)c * PIX + p);
            unsafeAtomicAdd(&s_l[c][lab.x], v.x);
            unsafeAtomicAdd(&s_l[c][lab.y], v.y);
            unsafeAtomicAdd(&s_l[c][lab.z], v.z);
            unsafeAtomicAdd(&s_l[c][lab.w], v.w);
            q0 = fmaf(v.x, v.x, q0);
            q1 = fmaf(v.y, v.y, q1);
            q2 = fmaf(v.z, v.z, q2);
            q3 = fmaf(v.w, v.w, q3);
        }
        unsafeAtomicAdd(&q_l[lab.x], q0);
        unsafeAtomicAdd(&q_l[lab.y], q1);
        unsafeAtomicAdd(&q_l[lab.z], q2);
        unsafeAtomicAdd(&q_l[lab.w], q3);
        unsafeAtomicAdd(&c_l[lab.x], 1.f);
        unsafeAtomicAdd(&c_l[lab.y], 1.f);
        unsafeAtomicAdd(&c_l[lab.z], 1.f);
        unsafeAtomicAdd(&c_l[lab.w], 1.f);
    }
    __syncthreads();

    if (tid < LBL) {
        const int l = tid;
        const float cnt = c_l[l];
        const float q   = q_l[l];
        float sum2 = 0.f;
        #pragma unroll
        for (int c = 0; c < CH; ++c) sum2 = fmaf(s_l[c][l], s_l[c][l], sum2);
        float var_sum = 0.f;
        if (cnt > 1.f) var_sum = (q - sum2 / cnt) / (cnt - 1.f);
        float v       = (l != 0) ? var_sum : 0.f;
        float present = (l != 0 && cnt > 0.f) ? 1.f : 0.f;
        #pragma unroll
        for (int off = 32; off > 0; off >>= 1) {
            v       += __shfl_down(v, off);
            present += __shfl_down(present, off);
        }
        if (l == 0)
            unsafeAtomicAdd(out, v / (present + 1e-8f) / (float)BATCH);
    }
}

extern "C" void kernel_launch(void* const* d_in, const int* in_sizes, int n_in,
                              void* d_out, int out_size, void* d_ws, size_t ws_size,
                              hipStream_t stream)
{
    const float* x  = (const float*)d_in[0];
    const int*   tg = (const int*)d_in[1];
    float* out = (float*)d_out;
    float* ws  = (float*)d_ws;

    if (ws_size >= (size_t)WS_FLOATS * sizeof(float)) {
        zero_ws<<<(WS_FLOATS + TPB - 1) / TPB, TPB, 0, stream>>>(ws);
        dim3 grid(BPB, BATCH);
        seg_onehot_mfma<<<grid, TPB, 0, stream>>>(x, tg, ws, ws + Q_OFF, ws + C_OFF);
        finalize<<<1, 1024, 0, stream>>>(ws, ws + Q_OFF, ws + C_OFF, out);
    } else {
        hipMemsetAsync(d_out, 0, sizeof(float), stream);
        fallback_all<<<BATCH, 1024, 0, stream>>>(x, tg, out);
    }
}